// Round 9
// baseline (184.424 us; speedup 1.0000x reference)
//
#include <hip/hip_runtime.h>

#define NN 100000
#define NE 1600000
#define HID 64
#define NBUK 391              // buckets of 256 node ids
#define SRCBITS 17
#define SRCMASK 0x1FFFF
#define EBLK 4096             // edges per fill block
#define GE2 ((NE + EBLK - 1) / EBLK)        // 391 edge-blocks
#define BSTRIDE 6144          // bbuf slots per bucket (mean 4096, >25 sigma headroom)
#define CSTRIDE 8192          // csr slots per bucket (4096 + 8-align pad <= 1792 + slack)

typedef __attribute__((ext_vector_type(8))) short bf16x8;
typedef __attribute__((ext_vector_type(4))) float f32x4;

__device__ __forceinline__ unsigned short f2bf(float f) {   // RTNE
    unsigned int x = __float_as_uint(f);
    return (unsigned short)((x + 0x7FFFu + ((x >> 16) & 1u)) >> 16);
}
__device__ __forceinline__ float bflo(unsigned int u) { return __uint_as_float(u << 16); }
__device__ __forceinline__ float bfhi(unsigned int u) { return __uint_as_float(u & 0xFFFF0000u); }

// ---- prep: W2 -> bf16 w2t[n][72] once; zero sentinel rows ------------------
__global__ void k_prep(const float* __restrict__ W2, unsigned short* __restrict__ w2t,
                       float* __restrict__ xs, unsigned short* __restrict__ hs) {
    int t = threadIdx.x;  // 256, 1 block
    for (int i = t; i < 4096; i += 256) {      // W2 [k][n] fp32 -> [n][k] bf16
        int k = i >> 6, n = i & 63;
        w2t[n * 72 + k] = f2bf(W2[i]);
    }
    if (t < 64) hs[NN * 64 + t] = 0;           // hs sentinel row
    if (t == 64) ((float4*)xs)[NN] = make_float4(0.f, 0.f, 0.f, 0.f);
}

// ---- fill1: stage 4096 edges in LDS, bucket-histogram, reserve bbuf space
// via ONE global atomic per (bucket,block), scatter packed edges. ------------
__global__ void __launch_bounds__(256)
k_fill1(const int* __restrict__ ei, int* __restrict__ gcnt,
        unsigned int* __restrict__ bbuf) {
    __shared__ int s_src[EBLK];   // 16 KB
    __shared__ int s_dst[EBLK];   // 16 KB
    __shared__ int s_hist[NBUK];  // hist, then absolute positions
    __shared__ int s_flag;
    int t = threadIdx.x;  // 256
    int b = blockIdx.x;

    for (int i = t; i < NBUK; i += 256) s_hist[i] = 0;
    if (t < 64) {   // int64 edges have all-zero odd int32 words
        unsigned long long bal = __ballot(ei[2 * t + 1] != 0);
        if (t == 0) s_flag = (bal == 0ULL) ? 1 : 0;  // 1 => int64 layout
    }
    __syncthreads();
    int f = s_flag;
    int base = b * EBLK;
    int m = NE - base; if (m > EBLK) m = EBLK;

    if (f) {                               // int64: int4 = 2 edges' words
        const int4* ps = (const int4*)ei;
        const int4* pd = (const int4*)(ei + 2 * (size_t)NE);
#pragma unroll
        for (int k = 0; k < EBLK / 512; ++k) {
            int e = base + k * 512 + t * 2;
            if (e < NE) {                  // NE even, e even -> e+1 valid
                int4 vs = ps[e >> 1];
                int4 vd = pd[e >> 1];
                int l = e - base;
                s_src[l] = vs.x;     s_dst[l] = vd.x;
                s_src[l + 1] = vs.z; s_dst[l + 1] = vd.z;
                atomicAdd(&s_hist[vd.x >> 8], 1);
                atomicAdd(&s_hist[vd.z >> 8], 1);
            }
        }
    } else {                               // int32: int4 = 4 edges
        const int4* ps = (const int4*)ei;
        const int4* pd = (const int4*)(ei + NE);
#pragma unroll
        for (int k = 0; k < EBLK / 1024; ++k) {
            int e = base + k * 1024 + t * 4;
            if (e < NE) {                  // NE % 4 == 0 -> whole quad valid
                int4 vs = ps[e >> 2];
                int4 vd = pd[e >> 2];
                int l = e - base;
                s_src[l] = vs.x; s_src[l + 1] = vs.y; s_src[l + 2] = vs.z; s_src[l + 3] = vs.w;
                s_dst[l] = vd.x; s_dst[l + 1] = vd.y; s_dst[l + 2] = vd.z; s_dst[l + 3] = vd.w;
                atomicAdd(&s_hist[vd.x >> 8], 1);
                atomicAdd(&s_hist[vd.y >> 8], 1);
                atomicAdd(&s_hist[vd.z >> 8], 1);
                atomicAdd(&s_hist[vd.w >> 8], 1);
            }
        }
    }
    __syncthreads();
    // reserve per-bucket chunks; s_hist[i] -> absolute bbuf position
    for (int i = t; i < NBUK; i += 256) {
        int c = s_hist[i];
        int r = c ? atomicAdd(&gcnt[i], c) : 0;
        s_hist[i] = i * BSTRIDE + r;
    }
    __syncthreads();
    for (int e = t; e < m; e += 256) {
        int d = s_dst[e];
        int p = atomicAdd(&s_hist[d >> 8], 1);
        bbuf[p] = ((unsigned int)(d & 255) << SRCBITS) | (unsigned int)s_src[e];
    }
}

// ---- passB: per-bucket sort -> 8-aligned sentinel-padded CSR + meta --------
// meta[node] = (csr_quad_index << 8) | deg. Pad slots = NN (zero row).
__global__ void __launch_bounds__(256)
k_passB(const unsigned int* __restrict__ bbuf, const int* __restrict__ gcnt,
        const float* __restrict__ x, int* __restrict__ meta,
        float* __restrict__ dinv, float* __restrict__ xs, int* __restrict__ csr) {
    __shared__ int hist[256];
    __shared__ int scn[256];
    __shared__ int cur[256];
    int t = threadIdx.x;  // 256
    int b = blockIdx.x;
    int sz = gcnt[b];
    const unsigned int* buf = bbuf + (size_t)b * BSTRIDE;
    hist[t] = 0;
    __syncthreads();
    for (int e = t; e < sz; e += 256)
        atomicAdd(&hist[buf[e] >> SRCBITS], 1);
    __syncthreads();
    int deg = hist[t];
    int pdeg = (deg + 7) & ~7;                // 8-slot aligned region
    scn[t] = pdeg; __syncthreads();
    for (int off = 1; off < 256; off <<= 1) {
        int u = (t >= off) ? scn[t - off] : 0;
        __syncthreads();
        scn[t] += u;
        __syncthreads();
    }
    int myoff = b * CSTRIDE + scn[t] - pdeg;
    int node = b * 256 + t;
    if (node < NN) {
        int dcl = deg < 255 ? deg : 255;
        meta[node] = ((myoff >> 2) << 8) | dcl;
        float d = 1.0f / sqrtf((float)(deg + 1));
        dinv[node] = d;
        float4 xv = ((const float4*)x)[node];
        float4 o; o.x = d * xv.x; o.y = d * xv.y; o.z = d * xv.z; o.w = d * xv.w;
        ((float4*)xs)[node] = o;
    }
    for (int p = deg; p < pdeg; ++p) csr[myoff + p] = NN;   // sentinel pad
    cur[t] = myoff;
    __syncthreads();
    for (int e = t; e < sz; e += 256) {
        unsigned int u = buf[e];
        int p = atomicAdd(&cur[u >> SRCBITS], 1);
        csr[p] = (int)(u & SRCMASK);
    }
}

// ---- fused: layer-1 aggregate (4 thr/node) + h1 + MFMA h1@W2 -> hs ---------
// 64 nodes/block, 256 threads. agg = dinv*(sum_nbr xs[s] + xs[self]).
// CSR 16B-aligned + sentinel-padded: int4 loads, NO guards. B-fragments read
// straight from global w2t (L2-hot broadcast, precomputed by k_prep).
// mfma_f32_16x16x32_bf16: A[m=lane&15][k=quad*8+j]; D col=lane&15, row=quad*4+reg.
__global__ void k_mm2(const float* __restrict__ xs, const int* __restrict__ meta,
                      const int* __restrict__ csr, const float* __restrict__ dinv,
                      const float* __restrict__ W1, const float* __restrict__ b1,
                      const unsigned short* __restrict__ w2t, unsigned short* __restrict__ hs) {
    __shared__ unsigned short h1b[64 * 72];   // [localNode][k], bf16, pad 72
    __shared__ float4 sPart[256];             // per-(part,node) partial sums
    __shared__ float4 sAgg[64];
    __shared__ float4 sXs[64];
    __shared__ float sW1[256];
    __shared__ float sb1[64];
    __shared__ float sdv[64];
    __shared__ int smeta[64];
    int t = threadIdx.x;  // 256
    int base = blockIdx.x * 64;
    if (t < 64) {
        int g = base + t;
        bool ok = (g < NN);
        smeta[t] = ok ? meta[g] : 0;
        sdv[t]  = ok ? dinv[g] : 0.f;
        sXs[t]  = ok ? ((const float4*)xs)[g] : make_float4(0.f, 0.f, 0.f, 0.f);
        sb1[t]  = b1[t];
    }
    sW1[t] = W1[t];
    __syncthreads();
    // aggregation: node_l = t&63, part = t>>6 handles int4-chunks part, part+4, ...
    {
        int node_l = t & 63, part = t >> 6;
        int mv = smeta[node_l];
        int n = mv & 255;
        int nb = mv >> 8;                      // int4 index into csr
        const int4* cp4 = (const int4*)csr;
        float4 s = make_float4(0.f, 0.f, 0.f, 0.f);
        for (int c = part; c * 4 < n; c += 4) {
            int4 q = cp4[nb + c];              // pad slots = NN -> zero row
            float4 v0 = ((const float4*)xs)[q.x];
            float4 v1 = ((const float4*)xs)[q.y];
            float4 v2 = ((const float4*)xs)[q.z];
            float4 v3 = ((const float4*)xs)[q.w];
            s.x += (v0.x + v1.x) + (v2.x + v3.x);
            s.y += (v0.y + v1.y) + (v2.y + v3.y);
            s.z += (v0.z + v1.z) + (v2.z + v3.z);
            s.w += (v0.w + v1.w) + (v2.w + v3.w);
        }
        sPart[t] = s;
    }
    __syncthreads();
    if (t < 64) {
        float4 a = sPart[t], b = sPart[t + 64], c = sPart[t + 128], d = sPart[t + 192];
        float4 xi = sXs[t];
        float dn = sdv[t];
        float4 o;
        o.x = dn * (a.x + b.x + c.x + d.x + xi.x);
        o.y = dn * (a.y + b.y + c.y + d.y + xi.y);
        o.z = dn * (a.z + b.z + c.z + d.z + xi.z);
        o.w = dn * (a.w + b.w + c.w + d.w + xi.w);
        sAgg[t] = o;
    }
    __syncthreads();
#pragma unroll
    for (int i = 0; i < 16; ++i) {            // h1 = relu(agg@W1+b1), bf16 to LDS
        int e = i * 256 + t;
        int nl = e >> 6, c = e & 63;
        float4 a = sAgg[nl];
        float h = fmaf(a.x, sW1[c], fmaf(a.y, sW1[64 + c],
                  fmaf(a.z, sW1[128 + c], fmaf(a.w, sW1[192 + c], sb1[c]))));
        h1b[nl * 72 + c] = f2bf(fmaxf(h, 0.f));
    }
    __syncthreads();
    int w = t >> 6, lane = t & 63, l15 = lane & 15, quad = lane >> 4;
    bf16x8 a0 = *(const bf16x8*)&h1b[(w * 16 + l15) * 72 + quad * 8];
    bf16x8 a1 = *(const bf16x8*)&h1b[(w * 16 + l15) * 72 + 32 + quad * 8];
    f32x4 acc[4];
#pragma unroll
    for (int nt = 0; nt < 4; ++nt) {
        bf16x8 bb0 = *(const bf16x8*)&w2t[(nt * 16 + l15) * 72 + quad * 8];
        bf16x8 bb1 = *(const bf16x8*)&w2t[(nt * 16 + l15) * 72 + 32 + quad * 8];
        f32x4 c = {0.f, 0.f, 0.f, 0.f};
        c = __builtin_amdgcn_mfma_f32_16x16x32_bf16(a0, bb0, c, 0, 0, 0);
        c = __builtin_amdgcn_mfma_f32_16x16x32_bf16(a1, bb1, c, 0, 0, 0);
        acc[nt] = c;
    }
#pragma unroll
    for (int nt = 0; nt < 4; ++nt) {
#pragma unroll
        for (int r = 0; r < 4; ++r) {
            int localn = w * 16 + quad * 4 + r;
            int g = base + localn;
            if (g < NN) hs[g * 64 + nt * 16 + l15] = f2bf(acc[nt][r] * sdv[localn]);
        }
    }
}

// ---- layer-2 gather + head: 16 lanes/node, 8 rows in flight, no guards -----
// bf16 rows (128B). Lane c: group g=c>>4 owns one node, sl=c&15 owns uint2
// (cols 4sl..4sl+3). All 16 lanes read the same csr int4s (HW broadcast);
// CSR regions are 8-aligned + sentinel-padded -> 2 unguarded int4s/iter.
__global__ void k_gather_head(const unsigned short* __restrict__ hs, const int* __restrict__ meta,
                              const int* __restrict__ csr, const float* __restrict__ dinv,
                              const float* __restrict__ b2, const float* __restrict__ Wl,
                              const float* __restrict__ bl, float* __restrict__ out) {
    int t = threadIdx.x;
    int c = t & 63;
    int g = c >> 4;
    int sl = c & 15;
    int node = blockIdx.x * 16 + (t >> 6) * 4 + g;
    int mv = meta[node];
    int n = mv & 255;
    int nb = mv >> 8;                            // int4 index into csr
    const uint2* hrow = (const uint2*)hs;        // 16 uint2 per row
    const int4* cp4 = (const int4*)csr;
    float4 A = make_float4(0.f, 0.f, 0.f, 0.f);
#define ACC2(u) do { \
    A.x += bflo(u.x); A.y += bfhi(u.x); A.z += bflo(u.y); A.w += bfhi(u.y); } while (0)
    for (int j8 = 0; j8 * 8 < n; ++j8) {
        int4 q0 = cp4[nb + 2 * j8];              // pad slots = NN -> zero row
        int4 q1 = cp4[nb + 2 * j8 + 1];
        uint2 u0 = hrow[q0.x * 16 + sl];
        uint2 u1 = hrow[q0.y * 16 + sl];
        uint2 u2 = hrow[q0.z * 16 + sl];
        uint2 u3 = hrow[q0.w * 16 + sl];
        uint2 u4 = hrow[q1.x * 16 + sl];
        uint2 u5 = hrow[q1.y * 16 + sl];
        uint2 u6 = hrow[q1.z * 16 + sl];
        uint2 u7 = hrow[q1.w * 16 + sl];
        ACC2(u0); ACC2(u1); ACC2(u2); ACC2(u3);
        ACC2(u4); ACC2(u5); ACC2(u6); ACC2(u7);
    }
    uint2 uS = hrow[node * 16 + sl];             // self loop
    ACC2(uS);
#undef ACC2
    float4 bv = ((const float4*)b2)[sl];
    float4 wv = ((const float4*)Wl)[sl];
    float dn = dinv[node];
    float v = fmaxf(fmaf(dn, A.x, bv.x), 0.f) * wv.x
            + fmaxf(fmaf(dn, A.y, bv.y), 0.f) * wv.y
            + fmaxf(fmaf(dn, A.z, bv.z), 0.f) * wv.z
            + fmaxf(fmaf(dn, A.w, bv.w), 0.f) * wv.w;
    // reduce across sl (lane bits 0..3)
    v += __shfl_xor(v, 1, 64);
    v += __shfl_xor(v, 2, 64);
    v += __shfl_xor(v, 4, 64);
    v += __shfl_xor(v, 8, 64);
    if (sl == 0) out[node] = v + bl[0];
}

extern "C" void kernel_launch(void* const* d_in, const int* in_sizes, int n_in,
                              void* d_out, int out_size, void* d_ws, size_t ws_size,
                              hipStream_t stream) {
    const float* x  = (const float*)d_in[0];
    const int*   ei = (const int*)d_in[1];
    const float* W1 = (const float*)d_in[2];
    const float* b1 = (const float*)d_in[3];
    const float* W2 = (const float*)d_in[4];
    const float* b2 = (const float*)d_in[5];
    const float* Wl = (const float*)d_in[6];
    const float* bl = (const float*)d_in[7];
    float* out = (float*)d_out;

    char* w = (char*)d_ws;
    float* dinv  = (float*)w;                  w += NN * 4;
    int*   metaA = (int*)w;                    w += NN * 4;
    float* xs    = (float*)w;                  w += (size_t)(NN + 1) * 16;          // +sentinel row
    unsigned short* hs = (unsigned short*)w;   w += (size_t)(NN + 1) * HID * 2;     // 12.8 MB (+sentinel)
    unsigned short* w2t = (unsigned short*)w;  w += ((64 * 72 * 2 + 255) & ~255);
    int*   gcnt  = (int*)w;                    w += ((NBUK + 63) & ~63) * 4;
    int*   csr   = (int*)w;                    w += (size_t)NBUK * CSTRIDE * 4;     // 12.8 MB aligned CSR
    w = (char*)(((size_t)w + 255) & ~(size_t)255);
    unsigned int* bbuf = (unsigned int*)w;     w += (size_t)NBUK * BSTRIDE * 4;     // 9.6 MB

    hipMemsetAsync(gcnt, 0, NBUK * sizeof(int), stream);
    hipLaunchKernelGGL(k_prep,  dim3(1),    dim3(256), 0, stream, W2, w2t, xs, hs);
    hipLaunchKernelGGL(k_fill1, dim3(GE2),  dim3(256), 0, stream, ei, gcnt, bbuf);
    hipLaunchKernelGGL(k_passB, dim3(NBUK), dim3(256), 0, stream,
                       bbuf, gcnt, x, metaA, dinv, xs, csr);
    hipLaunchKernelGGL(k_mm2, dim3((NN + 63) / 64), dim3(256), 0, stream,
                       xs, metaA, csr, dinv, W1, b1, w2t, hs);
    hipLaunchKernelGGL(k_gather_head, dim3(NN / 16), dim3(256), 0, stream,
                       hs, metaA, csr, dinv, b2, Wl, bl, out);
}

// Round 10
// 181.576 us; speedup vs baseline: 1.0157x; 1.0157x over previous
//
#include <hip/hip_runtime.h>

#define NN 100000
#define NE 1600000
#define HID 64
#define NBUK 391              // buckets of 256 node ids
#define SRCBITS 17
#define SRCMASK 0x1FFFF
#define EBLK 4096             // edges per fill block
#define GE2 ((NE + EBLK - 1) / EBLK)        // 391 edge-blocks
#define BSTRIDE 6144          // bbuf slots per bucket (mean 4096, >25 sigma headroom)
#define CSTRIDE 8192          // csr slots per bucket (mean ~5900 after 16-pad)

typedef __attribute__((ext_vector_type(8))) short bf16x8;
typedef __attribute__((ext_vector_type(4))) float f32x4;

__device__ __forceinline__ unsigned short f2bf(float f) {   // RTNE
    unsigned int x = __float_as_uint(f);
    return (unsigned short)((x + 0x7FFFu + ((x >> 16) & 1u)) >> 16);
}
__device__ __forceinline__ float bflo(unsigned int u) { return __uint_as_float(u << 16); }
__device__ __forceinline__ float bfhi(unsigned int u) { return __uint_as_float(u & 0xFFFF0000u); }

// ---- fill1: stage 4096 edges in LDS, bucket-histogram, reserve bbuf space
// via ONE global atomic per (bucket,block), scatter packed edges.
// Block 0 also zeroes the xs/hs sentinel rows (used by mm2/gather). ---------
__global__ void __launch_bounds__(256)
k_fill1(const int* __restrict__ ei, int* __restrict__ gcnt,
        unsigned int* __restrict__ bbuf, float* __restrict__ xs,
        unsigned short* __restrict__ hs) {
    __shared__ int s_src[EBLK];   // 16 KB
    __shared__ int s_dst[EBLK];   // 16 KB
    __shared__ int s_hist[NBUK];  // hist, then absolute positions
    __shared__ int s_flag;
    int t = threadIdx.x;  // 256
    int b = blockIdx.x;

    if (b == 0) {                 // sentinels (hs row NN, xs row NN)
        if (t < 64) hs[NN * 64 + t] = 0;
        if (t == 64) ((float4*)xs)[NN] = make_float4(0.f, 0.f, 0.f, 0.f);
    }
    for (int i = t; i < NBUK; i += 256) s_hist[i] = 0;
    if (t < 64) {   // int64 edges have all-zero odd int32 words
        unsigned long long bal = __ballot(ei[2 * t + 1] != 0);
        if (t == 0) s_flag = (bal == 0ULL) ? 1 : 0;  // 1 => int64 layout
    }
    __syncthreads();
    int f = s_flag;
    int base = b * EBLK;
    int m = NE - base; if (m > EBLK) m = EBLK;

    if (f) {                               // int64: int4 = 2 edges' words
        const int4* ps = (const int4*)ei;
        const int4* pd = (const int4*)(ei + 2 * (size_t)NE);
#pragma unroll
        for (int k = 0; k < EBLK / 512; ++k) {
            int e = base + k * 512 + t * 2;
            if (e < NE) {                  // NE even, e even -> e+1 valid
                int4 vs = ps[e >> 1];
                int4 vd = pd[e >> 1];
                int l = e - base;
                s_src[l] = vs.x;     s_dst[l] = vd.x;
                s_src[l + 1] = vs.z; s_dst[l + 1] = vd.z;
                atomicAdd(&s_hist[vd.x >> 8], 1);
                atomicAdd(&s_hist[vd.z >> 8], 1);
            }
        }
    } else {                               // int32: int4 = 4 edges
        const int4* ps = (const int4*)ei;
        const int4* pd = (const int4*)(ei + NE);
#pragma unroll
        for (int k = 0; k < EBLK / 1024; ++k) {
            int e = base + k * 1024 + t * 4;
            if (e < NE) {                  // NE % 4 == 0 -> whole quad valid
                int4 vs = ps[e >> 2];
                int4 vd = pd[e >> 2];
                int l = e - base;
                s_src[l] = vs.x; s_src[l + 1] = vs.y; s_src[l + 2] = vs.z; s_src[l + 3] = vs.w;
                s_dst[l] = vd.x; s_dst[l + 1] = vd.y; s_dst[l + 2] = vd.z; s_dst[l + 3] = vd.w;
                atomicAdd(&s_hist[vd.x >> 8], 1);
                atomicAdd(&s_hist[vd.y >> 8], 1);
                atomicAdd(&s_hist[vd.z >> 8], 1);
                atomicAdd(&s_hist[vd.w >> 8], 1);
            }
        }
    }
    __syncthreads();
    // reserve per-bucket chunks; s_hist[i] -> absolute bbuf position
    for (int i = t; i < NBUK; i += 256) {
        int c = s_hist[i];
        int r = c ? atomicAdd(&gcnt[i], c) : 0;
        s_hist[i] = i * BSTRIDE + r;
    }
    __syncthreads();
    for (int e = t; e < m; e += 256) {
        int d = s_dst[e];
        int p = atomicAdd(&s_hist[d >> 8], 1);
        bbuf[p] = ((unsigned int)(d & 255) << SRCBITS) | (unsigned int)s_src[e];
    }
}

// ---- passB: per-bucket sort -> 16-aligned sentinel-padded CSR + meta -------
// meta[node] = (csr_quad_index << 8) | deg. Pad slots = NN (zero row).
__global__ void __launch_bounds__(256)
k_passB(const unsigned int* __restrict__ bbuf, const int* __restrict__ gcnt,
        const float* __restrict__ x, int* __restrict__ meta,
        float* __restrict__ dinv, float* __restrict__ xs, int* __restrict__ csr) {
    __shared__ int hist[256];
    __shared__ int scn[256];
    __shared__ int cur[256];
    int t = threadIdx.x;  // 256
    int b = blockIdx.x;
    int sz = gcnt[b];
    const unsigned int* buf = bbuf + (size_t)b * BSTRIDE;
    hist[t] = 0;
    __syncthreads();
    for (int e = t; e < sz; e += 256)
        atomicAdd(&hist[buf[e] >> SRCBITS], 1);
    __syncthreads();
    int deg = hist[t];
    int pdeg = (deg + 15) & ~15;              // 16-slot aligned region
    scn[t] = pdeg; __syncthreads();
    for (int off = 1; off < 256; off <<= 1) {
        int u = (t >= off) ? scn[t - off] : 0;
        __syncthreads();
        scn[t] += u;
        __syncthreads();
    }
    int myoff = b * CSTRIDE + scn[t] - pdeg;
    int node = b * 256 + t;
    if (node < NN) {
        int dcl = deg < 255 ? deg : 255;
        meta[node] = ((myoff >> 2) << 8) | dcl;
        float d = 1.0f / sqrtf((float)(deg + 1));
        dinv[node] = d;
        float4 xv = ((const float4*)x)[node];
        float4 o; o.x = d * xv.x; o.y = d * xv.y; o.z = d * xv.z; o.w = d * xv.w;
        ((float4*)xs)[node] = o;
    }
    for (int p = deg; p < pdeg; ++p) csr[myoff + p] = NN;   // sentinel pad
    cur[t] = myoff;
    __syncthreads();
    for (int e = t; e < sz; e += 256) {
        unsigned int u = buf[e];
        int p = atomicAdd(&cur[u >> SRCBITS], 1);
        csr[p] = (int)(u & SRCMASK);
    }
}

// ---- fused: layer-1 aggregate (4 thr/node) + h1 + MFMA h1@W2 -> hs ---------
// 64 nodes/block, 256 threads. agg = dinv*(sum_nbr xs[s] + xs[self]).
// CSR 16B-aligned + sentinel-padded: int4 loads, NO guards. W2 staged in LDS
// as bf16 [n][k] (R2 measured-best config).
// mfma_f32_16x16x32_bf16: A[m=lane&15][k=quad*8+j]; D col=lane&15, row=quad*4+reg.
__global__ void k_mm2(const float* __restrict__ xs, const int* __restrict__ meta,
                      const int* __restrict__ csr, const float* __restrict__ dinv,
                      const float* __restrict__ W1, const float* __restrict__ b1,
                      const float* __restrict__ W2, unsigned short* __restrict__ hs) {
    __shared__ unsigned short h1b[64 * 72];   // [localNode][k], bf16, pad 72
    __shared__ unsigned short w2t[64 * 72];   // [n][k], bf16 (W2 transposed)
    __shared__ float4 sPart[256];             // per-(part,node) partial sums
    __shared__ float4 sAgg[64];
    __shared__ float4 sXs[64];
    __shared__ float sW1[256];
    __shared__ float sb1[64];
    __shared__ float sdv[64];
    __shared__ int smeta[64];
    int t = threadIdx.x;  // 256
    int base = blockIdx.x * 64;
    if (t < 64) {
        int g = base + t;
        bool ok = (g < NN);
        smeta[t] = ok ? meta[g] : 0;
        sdv[t]  = ok ? dinv[g] : 0.f;
        sXs[t]  = ok ? ((const float4*)xs)[g] : make_float4(0.f, 0.f, 0.f, 0.f);
        sb1[t]  = b1[t];
    }
    sW1[t] = W1[t];
    for (int i = t; i < 4096; i += 256) {     // W2 [k][n] fp32 -> w2t [n][k] bf16
        int k = i >> 6, n = i & 63;
        w2t[n * 72 + k] = f2bf(W2[i]);
    }
    __syncthreads();
    // aggregation: node_l = t&63, part = t>>6 handles int4-chunks part, part+4, ...
    {
        int node_l = t & 63, part = t >> 6;
        int mv = smeta[node_l];
        int n = mv & 255;
        int nb = mv >> 8;                      // int4 index into csr
        const int4* cp4 = (const int4*)csr;
        float4 s = make_float4(0.f, 0.f, 0.f, 0.f);
        for (int c = part; c * 4 < n; c += 4) {
            int4 q = cp4[nb + c];              // pad slots = NN -> zero row
            float4 v0 = ((const float4*)xs)[q.x];
            float4 v1 = ((const float4*)xs)[q.y];
            float4 v2 = ((const float4*)xs)[q.z];
            float4 v3 = ((const float4*)xs)[q.w];
            s.x += (v0.x + v1.x) + (v2.x + v3.x);
            s.y += (v0.y + v1.y) + (v2.y + v3.y);
            s.z += (v0.z + v1.z) + (v2.z + v3.z);
            s.w += (v0.w + v1.w) + (v2.w + v3.w);
        }
        sPart[t] = s;
    }
    __syncthreads();
    if (t < 64) {
        float4 a = sPart[t], b = sPart[t + 64], c = sPart[t + 128], d = sPart[t + 192];
        float4 xi = sXs[t];
        float dn = sdv[t];
        float4 o;
        o.x = dn * (a.x + b.x + c.x + d.x + xi.x);
        o.y = dn * (a.y + b.y + c.y + d.y + xi.y);
        o.z = dn * (a.z + b.z + c.z + d.z + xi.z);
        o.w = dn * (a.w + b.w + c.w + d.w + xi.w);
        sAgg[t] = o;
    }
    __syncthreads();
#pragma unroll
    for (int i = 0; i < 16; ++i) {            // h1 = relu(agg@W1+b1), bf16 to LDS
        int e = i * 256 + t;
        int nl = e >> 6, c = e & 63;
        float4 a = sAgg[nl];
        float h = fmaf(a.x, sW1[c], fmaf(a.y, sW1[64 + c],
                  fmaf(a.z, sW1[128 + c], fmaf(a.w, sW1[192 + c], sb1[c]))));
        h1b[nl * 72 + c] = f2bf(fmaxf(h, 0.f));
    }
    __syncthreads();
    int w = t >> 6, lane = t & 63, l15 = lane & 15, quad = lane >> 4;
    bf16x8 a0 = *(const bf16x8*)&h1b[(w * 16 + l15) * 72 + quad * 8];
    bf16x8 a1 = *(const bf16x8*)&h1b[(w * 16 + l15) * 72 + 32 + quad * 8];
    f32x4 acc[4];
#pragma unroll
    for (int nt = 0; nt < 4; ++nt) {
        bf16x8 bb0 = *(const bf16x8*)&w2t[(nt * 16 + l15) * 72 + quad * 8];
        bf16x8 bb1 = *(const bf16x8*)&w2t[(nt * 16 + l15) * 72 + 32 + quad * 8];
        f32x4 c = {0.f, 0.f, 0.f, 0.f};
        c = __builtin_amdgcn_mfma_f32_16x16x32_bf16(a0, bb0, c, 0, 0, 0);
        c = __builtin_amdgcn_mfma_f32_16x16x32_bf16(a1, bb1, c, 0, 0, 0);
        acc[nt] = c;
    }
#pragma unroll
    for (int nt = 0; nt < 4; ++nt) {
#pragma unroll
        for (int r = 0; r < 4; ++r) {
            int localn = w * 16 + quad * 4 + r;
            int g = base + localn;
            if (g < NN) hs[g * 64 + nt * 16 + l15] = f2bf(acc[nt][r] * sdv[localn]);
        }
    }
}

// ---- layer-2 gather + head: 16 lanes/node, 16 rows in flight, no guards ----
// bf16 rows (128B). Lane c: group g=c>>4 owns one node, sl=c&15 owns uint2
// (cols 4sl..4sl+3). All 16 lanes read the same csr int4s (HW broadcast);
// CSR regions are 16-aligned + sentinel-padded -> 4 unguarded int4s/iter,
// 16 independent row loads in flight (latency probe vs R9's 8).
__global__ void k_gather_head(const unsigned short* __restrict__ hs, const int* __restrict__ meta,
                              const int* __restrict__ csr, const float* __restrict__ dinv,
                              const float* __restrict__ b2, const float* __restrict__ Wl,
                              const float* __restrict__ bl, float* __restrict__ out) {
    int t = threadIdx.x;
    int c = t & 63;
    int g = c >> 4;
    int sl = c & 15;
    int node = blockIdx.x * 16 + (t >> 6) * 4 + g;
    int mv = meta[node];
    int n = mv & 255;
    int nb = mv >> 8;                            // int4 index into csr
    const uint2* hrow = (const uint2*)hs;        // 16 uint2 per row
    const int4* cp4 = (const int4*)csr;
    float4 A = make_float4(0.f, 0.f, 0.f, 0.f);
#define ACC2(u) do { \
    A.x += bflo(u.x); A.y += bfhi(u.x); A.z += bflo(u.y); A.w += bfhi(u.y); } while (0)
    for (int j16 = 0; j16 * 16 < n; ++j16) {
        int4 q0 = cp4[nb + 4 * j16];             // pad slots = NN -> zero row
        int4 q1 = cp4[nb + 4 * j16 + 1];
        int4 q2 = cp4[nb + 4 * j16 + 2];
        int4 q3 = cp4[nb + 4 * j16 + 3];
        uint2 u0  = hrow[q0.x * 16 + sl];
        uint2 u1  = hrow[q0.y * 16 + sl];
        uint2 u2  = hrow[q0.z * 16 + sl];
        uint2 u3  = hrow[q0.w * 16 + sl];
        uint2 u4  = hrow[q1.x * 16 + sl];
        uint2 u5  = hrow[q1.y * 16 + sl];
        uint2 u6  = hrow[q1.z * 16 + sl];
        uint2 u7  = hrow[q1.w * 16 + sl];
        uint2 u8  = hrow[q2.x * 16 + sl];
        uint2 u9  = hrow[q2.y * 16 + sl];
        uint2 u10 = hrow[q2.z * 16 + sl];
        uint2 u11 = hrow[q2.w * 16 + sl];
        uint2 u12 = hrow[q3.x * 16 + sl];
        uint2 u13 = hrow[q3.y * 16 + sl];
        uint2 u14 = hrow[q3.z * 16 + sl];
        uint2 u15 = hrow[q3.w * 16 + sl];
        ACC2(u0);  ACC2(u1);  ACC2(u2);  ACC2(u3);
        ACC2(u4);  ACC2(u5);  ACC2(u6);  ACC2(u7);
        ACC2(u8);  ACC2(u9);  ACC2(u10); ACC2(u11);
        ACC2(u12); ACC2(u13); ACC2(u14); ACC2(u15);
    }
    uint2 uS = hrow[node * 16 + sl];             // self loop
    ACC2(uS);
#undef ACC2
    float4 bv = ((const float4*)b2)[sl];
    float4 wv = ((const float4*)Wl)[sl];
    float dn = dinv[node];
    float v = fmaxf(fmaf(dn, A.x, bv.x), 0.f) * wv.x
            + fmaxf(fmaf(dn, A.y, bv.y), 0.f) * wv.y
            + fmaxf(fmaf(dn, A.z, bv.z), 0.f) * wv.z
            + fmaxf(fmaf(dn, A.w, bv.w), 0.f) * wv.w;
    // reduce across sl (lane bits 0..3)
    v += __shfl_xor(v, 1, 64);
    v += __shfl_xor(v, 2, 64);
    v += __shfl_xor(v, 4, 64);
    v += __shfl_xor(v, 8, 64);
    if (sl == 0) out[node] = v + bl[0];
}

extern "C" void kernel_launch(void* const* d_in, const int* in_sizes, int n_in,
                              void* d_out, int out_size, void* d_ws, size_t ws_size,
                              hipStream_t stream) {
    const float* x  = (const float*)d_in[0];
    const int*   ei = (const int*)d_in[1];
    const float* W1 = (const float*)d_in[2];
    const float* b1 = (const float*)d_in[3];
    const float* W2 = (const float*)d_in[4];
    const float* b2 = (const float*)d_in[5];
    const float* Wl = (const float*)d_in[6];
    const float* bl = (const float*)d_in[7];
    float* out = (float*)d_out;

    char* w = (char*)d_ws;
    float* dinv  = (float*)w;                  w += NN * 4;
    int*   metaA = (int*)w;                    w += NN * 4;
    float* xs    = (float*)w;                  w += (size_t)(NN + 1) * 16;          // +sentinel row
    unsigned short* hs = (unsigned short*)w;   w += (size_t)(NN + 1) * HID * 2;     // 12.8 MB (+sentinel)
    int*   gcnt  = (int*)w;                    w += ((NBUK + 63) & ~63) * 4;
    int*   csr   = (int*)w;                    w += (size_t)NBUK * CSTRIDE * 4;     // 12.8 MB aligned CSR
    w = (char*)(((size_t)w + 255) & ~(size_t)255);
    unsigned int* bbuf = (unsigned int*)w;     w += (size_t)NBUK * BSTRIDE * 4;     // 9.6 MB

    hipMemsetAsync(gcnt, 0, NBUK * sizeof(int), stream);
    hipLaunchKernelGGL(k_fill1, dim3(GE2),  dim3(256), 0, stream, ei, gcnt, bbuf, xs, hs);
    hipLaunchKernelGGL(k_passB, dim3(NBUK), dim3(256), 0, stream,
                       bbuf, gcnt, x, metaA, dinv, xs, csr);
    hipLaunchKernelGGL(k_mm2, dim3((NN + 63) / 64), dim3(256), 0, stream,
                       xs, metaA, csr, dinv, W1, b1, W2, hs);
    hipLaunchKernelGGL(k_gather_head, dim3(NN / 16), dim3(256), 0, stream,
                       hs, metaA, csr, dinv, b2, Wl, bl, out);
}